// Round 22
// baseline (178.266 us; speedup 1.0000x reference)
//
#include <hip/hip_runtime.h>

typedef unsigned int u32;
typedef unsigned short u16;
typedef __bf16 bf16x8 __attribute__((ext_vector_type(8)));
typedef float f32x16 __attribute__((ext_vector_type(16)));
typedef u32 u32x4 __attribute__((ext_vector_type(4)));

#define HDIM 128
#define FIN  256
#define NCLS 40
#define NL   4
#define BN   16384      // bucket nodes (64 KB LDS)
#define NSL  32         // edge slices

__device__ __forceinline__ u16 f2b(float f){
  union { __bf16 h; u16 s; } u; u.h = (__bf16)f; return u.s;
}
__device__ __forceinline__ u32 pk(float a, float b){
  union { __bf16 h[2]; u32 w; } u; u.h[0] = (__bf16)a; u.h[1] = (__bf16)b; return u.w;
}
__device__ __forceinline__ float ubf(u32 hbits){
  union { u32 w; float f; } u; u.w = hbits << 16; return u.f;
}
__device__ __forceinline__ float dinv(float d){ return d > 0.f ? rsqrtf(d) : 0.f; }

// Fragment-major index, 128-col weight block (lay/dec path, R7-verified):
__device__ __forceinline__ int fragIdx128(int row, int k){
  return (((((row >> 5) * 8 + (k >> 4)) * 2 + ((k >> 3) & 1)) * 32 + (row & 31)) * 8) + (k & 7);
}
// Fragment-major index, 64-col chunk (enc path, R17-verified):
__device__ __forceinline__ int fragIdx64(int row, int k){
  return (((((row >> 5) * 4 + (k >> 4)) * 2 + ((k >> 3) & 1)) * 32 + (row & 31)) * 8) + (k & 7);
}

// async linear 16 KB stage: 4 waves x 4 issues x (64 lanes x 16 B)
__device__ __forceinline__ void stage16k_async(u16* lds, const u16* src, int wv, int lane){
  #pragma unroll
  for(int i = 0; i < 4; i++){
    const int off = (wv * 4 + i) * 1024;
    __builtin_amdgcn_global_load_lds(
      (const __attribute__((address_space(1))) void*)((const char*)src + off + lane * 16),
      (__attribute__((address_space(3))) void*)((char*)lds + off),
      16, 0, 0);
  }
}

// async linear 32 KB stage: 4 waves x 8 issues x (64 lanes x 16 B)
__device__ __forceinline__ void stage32k_async(u16* lds, const u16* src, int wv, int lane){
  #pragma unroll
  for(int i = 0; i < 8; i++){
    const int off = (wv * 8 + i) * 1024;
    __builtin_amdgcn_global_load_lds(
      (const __attribute__((address_space(1))) void*)((const char*)src + off + lane * 16),
      (__attribute__((address_space(3))) void*)((char*)lds + off),
      16, 0, 0);
  }
}

// ---------------- prep: weights -> bf16 fragment-major (R17-verified) ----------------
__global__ void prep_kernel(const float* __restrict__ encW, const float* __restrict__ Wraw,
                            const float* __restrict__ decW,
                            u16* __restrict__ encF, u16* __restrict__ weffF, u16* __restrict__ decB){
  int b = blockIdx.x, t = threadIdx.x;
  if(b < 512){
    int i = b * 64 + t;
    int row = i >> 8, k = i & 255;
    int chunk = k >> 6, kk = k & 63;             // 4 chunks of 64 cols
    encF[chunk * 8192 + fragIdx64(row, kk)] = f2b(encW[i]);
  } else if(b < 1024){
    int idx = b - 512;
    int l = idx >> 7, i = idx & 127;
    const float* Wr = Wraw + (size_t)l * HDIM * (HDIM + 2);
    float w0a, w0b, s = 0.f;
    { int j = t;
      float v = (i < j) ? Wr[i*(HDIM+2)+j] : ((j < i) ? Wr[j*(HDIM+2)+i] : 0.f);
      w0a = v; s += fabsf(v); }
    { int j = t + 64;
      float v = (i < j) ? Wr[i*(HDIM+2)+j] : ((j < i) ? Wr[j*(HDIM+2)+i] : 0.f);
      w0b = v; s += fabsf(v); }
    #pragma unroll
    for(int d = 1; d < 64; d <<= 1) s += __shfl_xor(s, d, 64);
    float diag = Wr[i*(HDIM+2)+HDIM] * s + Wr[i*(HDIM+2)+HDIM+1];
    u16* o = weffF + (size_t)l * 16384;
    o[fragIdx128(i, t)]      = f2b((t == i)      ? diag : w0a);
    o[fragIdx128(i, t + 64)] = f2b((t + 64 == i) ? diag : w0b);
  } else {
    int idx = b - 1024;
    int i = idx * 64 + t;
    int c = i >> 7, k = i & 127;
    decB[i] = (c < NCLS) ? f2b(decW[c * HDIM + k]) : (u16)0;
  }
}

// ---------------- bucketed LDS scatter bodies (R13-verified logic) ----------------

template<int WEIGHTED>
__device__ void hist_body(float* buck, int b, int tid,
                          const int* __restrict__ idx, const int* __restrict__ src,
                          const float* __restrict__ dv, float* __restrict__ partial,
                          int E, int Nn, int NB, int chunk)
{
  const int g = b % NB;
  const int s = b / NB;
  const int lo = g << 14;

  for(int i = tid; i < BN; i += 256) buck[i] = 0.f;
  __syncthreads();

  long e0 = (long)s * chunk;
  long e1 = (long)E < e0 + chunk ? (long)E : e0 + chunk;
  if(e0 < e1){
    long ng = (e1 - e0) >> 2;
    for(long gi = tid; gi < ng; gi += 256){
      long e = e0 + gi * 4;
      int4 c = *(const int4*)(idx + e);
      int4 r;
      if(WEIGHTED) r = *(const int4*)(src + e);
      int k;
      k = c.x - lo; if((u32)k < (u32)BN) atomicAdd(&buck[k], WEIGHTED ? dv[r.x] : 1.f);
      k = c.y - lo; if((u32)k < (u32)BN) atomicAdd(&buck[k], WEIGHTED ? dv[r.y] : 1.f);
      k = c.z - lo; if((u32)k < (u32)BN) atomicAdd(&buck[k], WEIGHTED ? dv[r.z] : 1.f);
      k = c.w - lo; if((u32)k < (u32)BN) atomicAdd(&buck[k], WEIGHTED ? dv[r.w] : 1.f);
    }
    long et = e0 + ng * 4;
    if(et + tid < e1){
      long e = et + tid;
      int k = idx[e] - lo;
      if((u32)k < (u32)BN) atomicAdd(&buck[k], WEIGHTED ? dv[src[e]] : 1.f);
    }
  }
  __syncthreads();

  float* dst = partial + (size_t)s * ((size_t)NB << 14) + lo;
  int hi = Nn - lo < BN ? Nn - lo : BN;
  for(int i = tid; i < hi; i += 256) dst[i] = buck[i];
}

template<int WEIGHTED>
__global__ void __launch_bounds__(256, 2)
hist_kernel(const int* __restrict__ idx, const int* __restrict__ src,
            const float* __restrict__ dv, float* __restrict__ partial,
            int E, int Nn, int NB, int chunk)
{
  __shared__ float buck[BN];
  hist_body<WEIGHTED>(buck, blockIdx.x, threadIdx.x, idx, src, dv, partial, E, Nn, NB, chunk);
}

template<int MODE>   // 0: out = dinv(sum);  1: out = dvin * sum  (coef)
__global__ void reduce_kernel(const float* __restrict__ partial, const float* __restrict__ dvin,
                              float* __restrict__ outv, int Nn, int NB, int S)
{
  int i = blockIdx.x * 256 + threadIdx.x;
  if(i >= Nn) return;
  const size_t NnPad = (size_t)NB << 14;
  float t = 0.f;
  for(int s = 0; s < S; s++) t += partial[(size_t)s * NnPad + i];
  outv[i] = MODE ? dvin[i] * t : (t > 0.f ? rsqrtf(t) : 0.f);
}

// ---------------- fallback edge pipeline (R9-verified, device-scope atomics) ----------------

__global__ void deg_kernel(const int* __restrict__ ei, float* __restrict__ deg, int E){
  long e = ((long)blockIdx.x * 256 + threadIdx.x) * 8;
  if(e + 7 < E){
    int4 v0 = *(const int4*)(ei + e);
    int4 v1 = *(const int4*)(ei + e + 4);
    atomicAdd(&deg[v0.x], 1.0f); atomicAdd(&deg[v0.y], 1.0f);
    atomicAdd(&deg[v0.z], 1.0f); atomicAdd(&deg[v0.w], 1.0f);
    atomicAdd(&deg[v1.x], 1.0f); atomicAdd(&deg[v1.y], 1.0f);
    atomicAdd(&deg[v1.z], 1.0f); atomicAdd(&deg[v1.w], 1.0f);
  } else {
    for(; e < E; e++) atomicAdd(&deg[ei[e]], 1.0f);
  }
}

__global__ void coef_kernel(const int* __restrict__ ei, const float* __restrict__ deg,
                            float* __restrict__ coef, int E){
  long e = ((long)blockIdx.x * 256 + threadIdx.x) * 8;
  if(e + 7 < E){
    int4 r0 = *(const int4*)(ei + e);
    int4 r1 = *(const int4*)(ei + e + 4);
    int4 c0 = *(const int4*)(ei + E + e);
    int4 c1 = *(const int4*)(ei + E + e + 4);
    atomicAdd(&coef[c0.x], dinv(deg[r0.x]) * dinv(deg[c0.x]));
    atomicAdd(&coef[c0.y], dinv(deg[r0.y]) * dinv(deg[c0.y]));
    atomicAdd(&coef[c0.z], dinv(deg[r0.z]) * dinv(deg[c0.z]));
    atomicAdd(&coef[c0.w], dinv(deg[r0.w]) * dinv(deg[c0.w]));
    atomicAdd(&coef[c1.x], dinv(deg[r1.x]) * dinv(deg[c1.x]));
    atomicAdd(&coef[c1.y], dinv(deg[r1.y]) * dinv(deg[c1.y]));
    atomicAdd(&coef[c1.z], dinv(deg[r1.z]) * dinv(deg[c1.z]));
    atomicAdd(&coef[c1.w], dinv(deg[r1.w]) * dinv(deg[c1.w]));
  } else {
    for(; e < E; e++){
      int r = ei[e], c = ei[E + e];
      atomicAdd(&coef[c], dinv(deg[r]) * dinv(deg[c]));
    }
  }
}

// ---------------- shared helpers ----------------
__device__ __forceinline__ bf16x8 buildBp(u32 P0, u32 P1, u32 P2, u32 P3, int hi){
  u32 S0 = hi ? P0 : P2;
  u32 S1 = hi ? P1 : P3;
  u32 R0 = __shfl_xor(S0, 32, 64);
  u32 R1 = __shfl_xor(S1, 32, 64);
  union { u32 w[4]; bf16x8 b; } u;
  u.w[0] = hi ? R0 : P0;
  u.w[1] = hi ? R1 : P1;
  u.w[2] = hi ? P2 : R0;
  u.w[3] = hi ? P3 : R1;
  return u.b;
}

// ---------------- enc body (R18/R19-verified): 4-chunk K-split, async weight stage ----------------
__device__ void enc_body(u16* lw, u16* xc, int blk, int tid,
                         const float* __restrict__ x, const float* __restrict__ enc_b,
                         const u16* __restrict__ encF, u32* __restrict__ h0F, int Nn)
{
  const int lane = tid & 63;
  const int wv   = tid >> 6;
  const int hi   = lane >> 5;
  const int ln   = lane & 31;
  const int nib  = wv * 32 + ln;

  f32x16 acc[4];
  #pragma unroll
  for(int nt = 0; nt < 4; nt++)
    #pragma unroll
    for(int i = 0; i < 16; i++) acc[nt][i] = 0.f;

  const int r0 = tid >> 4;          // 0..15
  const int c4 = (tid & 15) * 4;    // 0..60
  const int g  = c4 >> 3, j = c4 & 7;

  for(int chunk = 0; chunk < 4; chunk++){
    __syncthreads();
    // async weight stage (overlaps the xc transpose below)
    stage16k_async(lw, encF + chunk * 8192, wv, lane);
    // coalesced x chunk load + transpose to fragment layout (row-swizzled)
    #pragma unroll
    for(int i = 0; i < 8; i++){
      int r = i * 16 + r0;
      int gn = blk * 128 + r; if(gn >= Nn) gn = Nn - 1;
      float4 v = *(const float4*)(x + (size_t)gn * FIN + chunk * 64 + c4);
      u32* d = (u32*)(xc + g * 1024 + ((r ^ (g & 7)) << 3) + j);
      d[0] = pk(v.x, v.y);
      d[1] = pk(v.z, v.w);
    }
    __syncthreads();

    #pragma unroll
    for(int ksl = 0; ksl < 4; ksl++){
      #pragma unroll
      for(int nt = 0; nt < 4; nt++){
        const int gg = ksl * 2 + hi;
        const bf16x8 B = *(const bf16x8*)(xc + gg * 1024 + ((nib ^ (gg & 7)) << 3));
        const bf16x8 A = *(const bf16x8*)(lw + ((((nt * 4 + ksl) * 2 + hi) * 32 + ln) * 8));
        acc[nt] = __builtin_amdgcn_mfma_f32_32x32x16_bf16(A, B, acc[nt], 0, 0, 0);
      }
    }
  }

  u32* dst = h0F + (size_t)blk * 8192;
  #pragma unroll
  for(int nt = 0; nt < 4; nt++){
    #pragma unroll
    for(int q = 0; q < 4; q++){
      float4 eb = *(const float4*)(enc_b + nt * 32 + 8 * q + 4 * hi);
      acc[nt][4*q+0] += eb.x; acc[nt][4*q+1] += eb.y;
      acc[nt][4*q+2] += eb.z; acc[nt][4*q+3] += eb.w;
    }
    #pragma unroll
    for(int m = 0; m < 8; m++)
      dst[(nt * 8 + m) * 256 + tid] = pk(acc[nt][2*m], acc[nt][2*m+1]);
  }
}

// standalone enc (fallback path)
__global__ void __launch_bounds__(256, 2)
enc_kernel(const float* __restrict__ x, const float* __restrict__ enc_b,
           const u16* __restrict__ encF, u32* __restrict__ h0F, int Nn)
{
  __shared__ u16 lw[8192];
  __shared__ u16 xc[8192];
  enc_body(lw, xc, blockIdx.x, threadIdx.x, x, enc_b, encF, h0F, Nn);
}

// ---------------- kB: block-range fusion of enc (long, first) and hist<1> (short) ----------------
// Both ready after reduce0: enc is dv-independent, hist1 needs dv.
__global__ void __launch_bounds__(256, 2)
kB_kernel(const int* __restrict__ ei, const float* __restrict__ dv, float* __restrict__ partial,
          int E, int Nn, int NB, int chunk, int nEnc,
          const float* __restrict__ x, const float* __restrict__ enc_b,
          const u16* __restrict__ encF, u32* __restrict__ h0F)
{
  __shared__ __align__(16) char smem[65536];
  const int b = blockIdx.x, tid = threadIdx.x;
  if(b < nEnc){
    enc_body((u16*)smem, (u16*)(smem + 16384), b, tid, x, enc_b, encF, h0F, Nn);
  } else {
    hist_body<1>((float*)smem, b - nEnc, tid, ei + E, ei, dv, partial, E, Nn, NB, chunk);
  }
}

// ---------------- lay: R19-verified + inline coef (reduce1 folded in) ----------------
template<bool INLC>
__global__ void __launch_bounds__(256, 2)
lay_kernel(const float* __restrict__ W_b, const float* __restrict__ ext_w,
           const float* __restrict__ beta, const float* __restrict__ dec_b,
           const float* __restrict__ coef, const float* __restrict__ dv,
           const float* __restrict__ partial, int NB,
           const u32* __restrict__ h0F,
           const u16* __restrict__ weffF, const u16* __restrict__ decB,
           float* __restrict__ out, int Nn)
{
  __shared__ u16 lw[16384];        // 32 KB layer weights
  __shared__ u32 hns[16][256];     // 16 KB: pass-0 h carry (thread-private slots)

  const int tid  = threadIdx.x;
  const int lane = tid & 63;
  const int wv   = tid >> 6;
  const int hi   = lane >> 5;
  const int ln   = lane & 31;
  const int nib  = wv * 32 + ln;
  const int node = blockIdx.x * 128 + nib;
  const int nd   = node < Nn ? node : (Nn - 1);

  float cf;
  if(INLC){
    const size_t NnPad = (size_t)NB << 14;
    float s = 0.f;
    #pragma unroll 4
    for(int sl = 0; sl < NSL; sl++) s += partial[(size_t)sl * NnPad + nd];
    cf = dv[nd] * s;
  } else {
    cf = coef[nd];
  }

  u32 hp[32];
  const u32* srcH = h0F + (size_t)blockIdx.x * 8192;
  #pragma unroll
  for(int m = 0; m < 32; m++)
    hp[m] = srcH[m * 256 + tid];

  for(int l = 0; l < NL; l++){
    __syncthreads();
    stage32k_async(lw, weffF + l * 16384, wv, lane);
    __syncthreads();

    const float bet = beta[l];

    #pragma unroll
    for(int P = 0; P < 2; P++){
      f32x16 a0, a1;
      #pragma unroll
      for(int i = 0; i < 16; i++){ a0[i] = 0.f; a1[i] = 0.f; }

      #pragma unroll
      for(int ks = 0; ks < 8; ks++){
        const int wbase = (ks >> 1) * 8 + 4 * (ks & 1);
        bf16x8 B = buildBp(hp[wbase+0], hp[wbase+1], hp[wbase+2], hp[wbase+3], hi);
        const bf16x8 A0 = *(const bf16x8*)(lw + (((((2*P+0) * 8 + ks) * 2 + hi) * 32 + ln) * 8));
        const bf16x8 A1 = *(const bf16x8*)(lw + (((((2*P+1) * 8 + ks) * 2 + hi) * 32 + ln) * 8));
        a0 = __builtin_amdgcn_mfma_f32_32x32x16_bf16(A0, B, a0, 0, 0, 0);
        a1 = __builtin_amdgcn_mfma_f32_32x32x16_bf16(A1, B, a1, 0, 0, 0);
      }

      #pragma unroll
      for(int t = 0; t < 2; t++){
        const int nt = 2*P + t;
        f32x16& a = t ? a1 : a0;
        #pragma unroll
        for(int q = 0; q < 4; q++){
          const int fb = nt * 32 + 8 * q + 4 * hi;
          float4 wb = *(const float4*)(W_b   + l * HDIM + fb);
          float4 ew = *(const float4*)(ext_w + l * HDIM + fb);
          #pragma unroll
          for(int r2 = 0; r2 < 4; r2++){
            const int r = 4 * q + r2;
            float wbv = (r2==0)?wb.x:(r2==1)?wb.y:(r2==2)?wb.z:wb.w;
            float ewv = (r2==0)?ew.x:(r2==1)?ew.y:(r2==2)?ew.z:ew.w;
            u32 w0 = srcH[(nt * 8 + (r >> 1)) * 256 + tid];   // L2-resident h0 re-read
            u32 wc = hp[nt * 8 + (r >> 1)];
            float h0v = ubf((r & 1) ? (w0 >> 16) : (w0 & 0xffffu));
            float hv  = ubf((r & 1) ? (wc >> 16) : (wc & 0xffffu));
            float o = cf * (a[r] + wbv) - hv * ewv - bet * h0v;
            a[r] = hv + 0.1f * fmaxf(o, 0.f);
          }
        }
        #pragma unroll
        for(int m = 0; m < 8; m++){
          u32 w = pk(a[2*m], a[2*m+1]);
          if(P == 0) hns[nt * 8 + m][tid] = w;   // carry in LDS (thread-private)
          else       hp[nt * 8 + m] = w;
        }
      }
    }
    #pragma unroll
    for(int m = 0; m < 16; m++) hp[m] = hns[m][tid];
  }

  // ---- decoder: direct from L2 (verified path) ----
  f32x16 d0, d1;
  #pragma unroll
  for(int i = 0; i < 16; i++){ d0[i] = 0.f; d1[i] = 0.f; }

  #pragma unroll
  for(int ks = 0; ks < 8; ks++){
    const int wbase = (ks >> 1) * 8 + 4 * (ks & 1);
    bf16x8 B = buildBp(hp[wbase+0], hp[wbase+1], hp[wbase+2], hp[wbase+3], hi);
    const bf16x8 A0 = *(const bf16x8*)(decB + (0 * 32 + ln) * HDIM + ks * 16 + hi * 8);
    const bf16x8 A1 = *(const bf16x8*)(decB + (1 * 32 + ln) * HDIM + ks * 16 + hi * 8);
    d0 = __builtin_amdgcn_mfma_f32_32x32x16_bf16(A0, B, d0, 0, 0, 0);
    d1 = __builtin_amdgcn_mfma_f32_32x32x16_bf16(A1, B, d1, 0, 0, 0);
  }

  if(node < Nn){
    #pragma unroll
    for(int nt = 0; nt < 2; nt++){
      const f32x16& d = nt ? d1 : d0;
      #pragma unroll
      for(int q = 0; q < 4; q++){
        if(nt == 0 || q == 0){
          const int c0 = nt * 32 + 8 * q + 4 * hi;
          float4 db = *(const float4*)(dec_b + c0);
          float4 v;
          v.x = d[4*q+0] + db.x;
          v.y = d[4*q+1] + db.y;
          v.z = d[4*q+2] + db.z;
          v.w = d[4*q+3] + db.w;
          *(float4*)(out + (size_t)node * NCLS + c0) = v;
        }
      }
    }
  }
}

extern "C" void kernel_launch(void* const* d_in, const int* in_sizes, int n_in,
                              void* d_out, int out_size, void* d_ws, size_t ws_size,
                              hipStream_t stream){
  (void)n_in; (void)out_size;
  const float* x     = (const float*)d_in[0];
  const int*   ei    = (const int*)  d_in[1];
  const float* encW  = (const float*)d_in[2];
  const float* enc_b = (const float*)d_in[3];
  const float* Wraw  = (const float*)d_in[4];
  const float* W_b   = (const float*)d_in[5];
  const float* ext_w = (const float*)d_in[6];
  const float* beta  = (const float*)d_in[7];
  const float* decW  = (const float*)d_in[8];
  const float* dec_b = (const float*)d_in[9];
  float* out = (float*)d_out;
  const int Nn = in_sizes[0] / FIN;
  const int E  = in_sizes[1] / 2;
  const int nBlk = (Nn + 127) / 128;
  const int NB   = (Nn + BN - 1) / BN;
  const int chunk = (((E + NSL - 1) / NSL) + 3) & ~3;
  const int nbHist = NB * NSL;

  char* ws = (char*)d_ws;
  size_t szN = ((size_t)Nn * 4 + 511) & ~(size_t)511;
  float* coef = (float*)(ws);
  float* dv   = (float*)(ws + szN);               // fast: dinv; fallback: raw deg
  u16* encF   = (u16*)(ws + 2 * szN);
  u16* weffF  = (u16*)(ws + 2 * szN + 65536);
  u16* decB   = (u16*)(ws + 2 * szN + 65536 + 131072);
  u32* h0F    = (u32*)(ws + 2 * szN + 65536 + 131072 + 16384);
  float* partial = (float*)(ws + 2 * szN + 65536 + 131072 + 16384 + (size_t)nBlk * 32768);
  const size_t partialBytes = (size_t)NSL * ((size_t)NB << 14) * 4;
  const size_t need = 2 * szN + 65536 + 131072 + 16384 + (size_t)nBlk * 32768 + partialBytes;
  const bool fast = ws_size >= need;

  prep_kernel<<<1152, 64, 0, stream>>>(encW, Wraw, decW, encF, weffF, decB);
  const int ngrid = (Nn + 255) / 256;
  if(fast){
    // chain: hist0 -> reduce0(dv) -> [enc || hist1] -> lay (coef inlined)
    hist_kernel<0><<<nbHist, 256, 0, stream>>>(ei, ei, dv, partial, E, Nn, NB, chunk);
    reduce_kernel<0><<<ngrid, 256, 0, stream>>>(partial, dv, dv, Nn, NB, NSL);
    kB_kernel<<<nBlk + nbHist, 256, 0, stream>>>(ei, dv, partial, E, Nn, NB, chunk, nBlk,
                                                 x, enc_b, encF, h0F);
    lay_kernel<true><<<nBlk, 256, 0, stream>>>(W_b, ext_w, beta, dec_b, coef, dv, partial, NB,
                                               h0F, weffF, decB, out, Nn);
  } else {
    const int egrid = (int)((E / 8 + 255) / 256) + 1;
    hipMemsetAsync(ws, 0, 2 * szN, stream);
    deg_kernel <<<egrid, 256, 0, stream>>>(ei, dv, E);
    coef_kernel<<<egrid, 256, 0, stream>>>(ei, dv, coef, E);
    enc_kernel <<<nBlk, 256, 0, stream>>>(x, enc_b, encF, h0F, Nn);
    lay_kernel<false><<<nBlk, 256, 0, stream>>>(W_b, ext_w, beta, dec_b, coef, dv, partial, NB,
                                                h0F, weffF, decB, out, Nn);
  }
}

// Round 23
// 167.216 us; speedup vs baseline: 1.0661x; 1.0661x over previous
//
#include <hip/hip_runtime.h>

typedef unsigned int u32;
typedef unsigned short u16;
typedef __bf16 bf16x8 __attribute__((ext_vector_type(8)));
typedef float f32x16 __attribute__((ext_vector_type(16)));
typedef u32 u32x4 __attribute__((ext_vector_type(4)));

#define HDIM 128
#define FIN  256
#define NCLS 40
#define NL   4
#define BN   16384      // bucket nodes (64 KB LDS)
#define NSL  32         // edge slices

__device__ __forceinline__ u16 f2b(float f){
  union { __bf16 h; u16 s; } u; u.h = (__bf16)f; return u.s;
}
__device__ __forceinline__ u32 pk(float a, float b){
  union { __bf16 h[2]; u32 w; } u; u.h[0] = (__bf16)a; u.h[1] = (__bf16)b; return u.w;
}
__device__ __forceinline__ float ubf(u32 hbits){
  union { u32 w; float f; } u; u.w = hbits << 16; return u.f;
}
__device__ __forceinline__ float dinv(float d){ return d > 0.f ? rsqrtf(d) : 0.f; }

// Fragment-major index, 128-col weight block (lay/dec path, R7-verified):
__device__ __forceinline__ int fragIdx128(int row, int k){
  return (((((row >> 5) * 8 + (k >> 4)) * 2 + ((k >> 3) & 1)) * 32 + (row & 31)) * 8) + (k & 7);
}
// Fragment-major index, 64-col chunk (enc path, R17-verified):
__device__ __forceinline__ int fragIdx64(int row, int k){
  return (((((row >> 5) * 4 + (k >> 4)) * 2 + ((k >> 3) & 1)) * 32 + (row & 31)) * 8) + (k & 7);
}

// async linear 16 KB stage: 4 waves x 4 issues x (64 lanes x 16 B)
__device__ __forceinline__ void stage16k_async(u16* lds, const u16* src, int wv, int lane){
  #pragma unroll
  for(int i = 0; i < 4; i++){
    const int off = (wv * 4 + i) * 1024;
    __builtin_amdgcn_global_load_lds(
      (const __attribute__((address_space(1))) void*)((const char*)src + off + lane * 16),
      (__attribute__((address_space(3))) void*)((char*)lds + off),
      16, 0, 0);
  }
}

// async linear 32 KB stage: 4 waves x 8 issues x (64 lanes x 16 B)
__device__ __forceinline__ void stage32k_async(u16* lds, const u16* src, int wv, int lane){
  #pragma unroll
  for(int i = 0; i < 8; i++){
    const int off = (wv * 8 + i) * 1024;
    __builtin_amdgcn_global_load_lds(
      (const __attribute__((address_space(1))) void*)((const char*)src + off + lane * 16),
      (__attribute__((address_space(3))) void*)((char*)lds + off),
      16, 0, 0);
  }
}

// ---------------- prep body (R17-verified): b in [0,1152), t in [0,64) ----------------
__device__ void prep_body(int b, int t,
                          const float* __restrict__ encW, const float* __restrict__ Wraw,
                          const float* __restrict__ decW,
                          u16* __restrict__ encF, u16* __restrict__ weffF, u16* __restrict__ decB){
  if(b < 512){
    int i = b * 64 + t;
    int row = i >> 8, k = i & 255;
    int chunk = k >> 6, kk = k & 63;             // 4 chunks of 64 cols
    encF[chunk * 8192 + fragIdx64(row, kk)] = f2b(encW[i]);
  } else if(b < 1024){
    int idx = b - 512;
    int l = idx >> 7, i = idx & 127;
    const float* Wr = Wraw + (size_t)l * HDIM * (HDIM + 2);
    float w0a, w0b, s = 0.f;
    { int j = t;
      float v = (i < j) ? Wr[i*(HDIM+2)+j] : ((j < i) ? Wr[j*(HDIM+2)+i] : 0.f);
      w0a = v; s += fabsf(v); }
    { int j = t + 64;
      float v = (i < j) ? Wr[i*(HDIM+2)+j] : ((j < i) ? Wr[j*(HDIM+2)+i] : 0.f);
      w0b = v; s += fabsf(v); }
    #pragma unroll
    for(int d = 1; d < 64; d <<= 1) s += __shfl_xor(s, d, 64);
    float diag = Wr[i*(HDIM+2)+HDIM] * s + Wr[i*(HDIM+2)+HDIM+1];
    u16* o = weffF + (size_t)l * 16384;
    o[fragIdx128(i, t)]      = f2b((t == i)      ? diag : w0a);
    o[fragIdx128(i, t + 64)] = f2b((t + 64 == i) ? diag : w0b);
  } else {
    int idx = b - 1024;
    int i = idx * 64 + t;
    int c = i >> 7, k = i & 127;
    decB[i] = (c < NCLS) ? f2b(decW[c * HDIM + k]) : (u16)0;
  }
}

__global__ void prep_kernel(const float* __restrict__ encW, const float* __restrict__ Wraw,
                            const float* __restrict__ decW,
                            u16* __restrict__ encF, u16* __restrict__ weffF, u16* __restrict__ decB){
  prep_body(blockIdx.x, threadIdx.x, encW, Wraw, decW, encF, weffF, decB);
}

// ---------------- bucketed LDS scatter bodies (R13-verified logic) ----------------

template<int WEIGHTED>
__device__ void hist_body(float* buck, int b, int tid,
                          const int* __restrict__ idx, const int* __restrict__ src,
                          const float* __restrict__ dv, float* __restrict__ partial,
                          int E, int Nn, int NB, int chunk)
{
  const int g = b % NB;
  const int s = b / NB;
  const int lo = g << 14;

  for(int i = tid; i < BN; i += 256) buck[i] = 0.f;
  __syncthreads();

  long e0 = (long)s * chunk;
  long e1 = (long)E < e0 + chunk ? (long)E : e0 + chunk;
  if(e0 < e1){
    long ng = (e1 - e0) >> 2;
    for(long gi = tid; gi < ng; gi += 256){
      long e = e0 + gi * 4;
      int4 c = *(const int4*)(idx + e);
      int4 r;
      if(WEIGHTED) r = *(const int4*)(src + e);
      int k;
      k = c.x - lo; if((u32)k < (u32)BN) atomicAdd(&buck[k], WEIGHTED ? dv[r.x] : 1.f);
      k = c.y - lo; if((u32)k < (u32)BN) atomicAdd(&buck[k], WEIGHTED ? dv[r.y] : 1.f);
      k = c.z - lo; if((u32)k < (u32)BN) atomicAdd(&buck[k], WEIGHTED ? dv[r.z] : 1.f);
      k = c.w - lo; if((u32)k < (u32)BN) atomicAdd(&buck[k], WEIGHTED ? dv[r.w] : 1.f);
    }
    long et = e0 + ng * 4;
    if(et + tid < e1){
      long e = et + tid;
      int k = idx[e] - lo;
      if((u32)k < (u32)BN) atomicAdd(&buck[k], WEIGHTED ? dv[src[e]] : 1.f);
    }
  }
  __syncthreads();

  float* dst = partial + (size_t)s * ((size_t)NB << 14) + lo;
  int hi = Nn - lo < BN ? Nn - lo : BN;
  for(int i = tid; i < hi; i += 256) dst[i] = buck[i];
}

template<int WEIGHTED>
__global__ void __launch_bounds__(256, 2)
hist_kernel(const int* __restrict__ idx, const int* __restrict__ src,
            const float* __restrict__ dv, float* __restrict__ partial,
            int E, int Nn, int NB, int chunk)
{
  __shared__ float buck[BN];
  hist_body<WEIGHTED>(buck, blockIdx.x, threadIdx.x, idx, src, dv, partial, E, Nn, NB, chunk);
}

template<int MODE>   // 0: out = dinv(sum);  1: out = dvin * sum  (coef)
__global__ void reduce_kernel(const float* __restrict__ partial, const float* __restrict__ dvin,
                              float* __restrict__ outv, int Nn, int NB, int S)
{
  int i = blockIdx.x * 256 + threadIdx.x;
  if(i >= Nn) return;
  const size_t NnPad = (size_t)NB << 14;
  float t = 0.f;
  for(int s = 0; s < S; s++) t += partial[(size_t)s * NnPad + i];
  outv[i] = MODE ? dvin[i] * t : (t > 0.f ? rsqrtf(t) : 0.f);
}

// ---------------- kP: block-range fusion of hist<0> (short, first... actually prep short) ----
// prep (288 blocks, no LDS) and hist0 (224 blocks) are independent: prep reads weights,
// hist0 reads edges. Order: hist0 first (uses LDS heavily), prep after.
__global__ void __launch_bounds__(256, 2)
kP_kernel(const float* __restrict__ encW, const float* __restrict__ Wraw,
          const float* __restrict__ decW,
          u16* __restrict__ encF, u16* __restrict__ weffF, u16* __restrict__ decB,
          const int* __restrict__ ei, float* __restrict__ partial,
          int E, int Nn, int NB, int chunk, int nbHist)
{
  __shared__ __align__(16) float buck[BN];
  const int b = blockIdx.x, tid = threadIdx.x;
  if(b < nbHist){
    hist_body<0>(buck, b, tid, ei, ei, (const float*)nullptr, partial, E, Nn, NB, chunk);
  } else {
    const int pb = (b - nbHist) * 4 + (tid >> 6);   // original 64-thread prep block
    prep_body(pb, tid & 63, encW, Wraw, decW, encF, weffF, decB);
  }
}

// ---------------- fallback edge pipeline (R9-verified, device-scope atomics) ----------------

__global__ void deg_kernel(const int* __restrict__ ei, float* __restrict__ deg, int E){
  long e = ((long)blockIdx.x * 256 + threadIdx.x) * 8;
  if(e + 7 < E){
    int4 v0 = *(const int4*)(ei + e);
    int4 v1 = *(const int4*)(ei + e + 4);
    atomicAdd(&deg[v0.x], 1.0f); atomicAdd(&deg[v0.y], 1.0f);
    atomicAdd(&deg[v0.z], 1.0f); atomicAdd(&deg[v0.w], 1.0f);
    atomicAdd(&deg[v1.x], 1.0f); atomicAdd(&deg[v1.y], 1.0f);
    atomicAdd(&deg[v1.z], 1.0f); atomicAdd(&deg[v1.w], 1.0f);
  } else {
    for(; e < E; e++) atomicAdd(&deg[ei[e]], 1.0f);
  }
}

__global__ void coef_kernel(const int* __restrict__ ei, const float* __restrict__ deg,
                            float* __restrict__ coef, int E){
  long e = ((long)blockIdx.x * 256 + threadIdx.x) * 8;
  if(e + 7 < E){
    int4 r0 = *(const int4*)(ei + e);
    int4 r1 = *(const int4*)(ei + e + 4);
    int4 c0 = *(const int4*)(ei + E + e);
    int4 c1 = *(const int4*)(ei + E + e + 4);
    atomicAdd(&coef[c0.x], dinv(deg[r0.x]) * dinv(deg[c0.x]));
    atomicAdd(&coef[c0.y], dinv(deg[r0.y]) * dinv(deg[c0.y]));
    atomicAdd(&coef[c0.z], dinv(deg[r0.z]) * dinv(deg[c0.z]));
    atomicAdd(&coef[c0.w], dinv(deg[r0.w]) * dinv(deg[c0.w]));
    atomicAdd(&coef[c1.x], dinv(deg[r1.x]) * dinv(deg[c1.x]));
    atomicAdd(&coef[c1.y], dinv(deg[r1.y]) * dinv(deg[c1.y]));
    atomicAdd(&coef[c1.z], dinv(deg[r1.z]) * dinv(deg[c1.z]));
    atomicAdd(&coef[c1.w], dinv(deg[r1.w]) * dinv(deg[c1.w]));
  } else {
    for(; e < E; e++){
      int r = ei[e], c = ei[E + e];
      atomicAdd(&coef[c], dinv(deg[r]) * dinv(deg[c]));
    }
  }
}

// ---------------- shared helpers ----------------
__device__ __forceinline__ bf16x8 buildBp(u32 P0, u32 P1, u32 P2, u32 P3, int hi){
  u32 S0 = hi ? P0 : P2;
  u32 S1 = hi ? P1 : P3;
  u32 R0 = __shfl_xor(S0, 32, 64);
  u32 R1 = __shfl_xor(S1, 32, 64);
  union { u32 w[4]; bf16x8 b; } u;
  u.w[0] = hi ? R0 : P0;
  u.w[1] = hi ? R1 : P1;
  u.w[2] = hi ? P2 : R0;
  u.w[3] = hi ? P3 : R1;
  return u.b;
}

// ---------------- enc body (R18/R19-verified): 4-chunk K-split, async weight stage ----------------
__device__ void enc_body(u16* lw, u16* xc, int blk, int tid,
                         const float* __restrict__ x, const float* __restrict__ enc_b,
                         const u16* __restrict__ encF, u32* __restrict__ h0F, int Nn)
{
  const int lane = tid & 63;
  const int wv   = tid >> 6;
  const int hi   = lane >> 5;
  const int ln   = lane & 31;
  const int nib  = wv * 32 + ln;

  f32x16 acc[4];
  #pragma unroll
  for(int nt = 0; nt < 4; nt++)
    #pragma unroll
    for(int i = 0; i < 16; i++) acc[nt][i] = 0.f;

  const int r0 = tid >> 4;          // 0..15
  const int c4 = (tid & 15) * 4;    // 0..60
  const int g  = c4 >> 3, j = c4 & 7;

  for(int chunk = 0; chunk < 4; chunk++){
    __syncthreads();
    stage16k_async(lw, encF + chunk * 8192, wv, lane);
    #pragma unroll
    for(int i = 0; i < 8; i++){
      int r = i * 16 + r0;
      int gn = blk * 128 + r; if(gn >= Nn) gn = Nn - 1;
      float4 v = *(const float4*)(x + (size_t)gn * FIN + chunk * 64 + c4);
      u32* d = (u32*)(xc + g * 1024 + ((r ^ (g & 7)) << 3) + j);
      d[0] = pk(v.x, v.y);
      d[1] = pk(v.z, v.w);
    }
    __syncthreads();

    #pragma unroll
    for(int ksl = 0; ksl < 4; ksl++){
      #pragma unroll
      for(int nt = 0; nt < 4; nt++){
        const int gg = ksl * 2 + hi;
        const bf16x8 B = *(const bf16x8*)(xc + gg * 1024 + ((nib ^ (gg & 7)) << 3));
        const bf16x8 A = *(const bf16x8*)(lw + ((((nt * 4 + ksl) * 2 + hi) * 32 + ln) * 8));
        acc[nt] = __builtin_amdgcn_mfma_f32_32x32x16_bf16(A, B, acc[nt], 0, 0, 0);
      }
    }
  }

  u32* dst = h0F + (size_t)blk * 8192;
  #pragma unroll
  for(int nt = 0; nt < 4; nt++){
    #pragma unroll
    for(int q = 0; q < 4; q++){
      float4 eb = *(const float4*)(enc_b + nt * 32 + 8 * q + 4 * hi);
      acc[nt][4*q+0] += eb.x; acc[nt][4*q+1] += eb.y;
      acc[nt][4*q+2] += eb.z; acc[nt][4*q+3] += eb.w;
    }
    #pragma unroll
    for(int m = 0; m < 8; m++)
      dst[(nt * 8 + m) * 256 + tid] = pk(acc[nt][2*m], acc[nt][2*m+1]);
  }
}

// standalone enc (fallback path)
__global__ void __launch_bounds__(256, 2)
enc_kernel(const float* __restrict__ x, const float* __restrict__ enc_b,
           const u16* __restrict__ encF, u32* __restrict__ h0F, int Nn)
{
  __shared__ u16 lw[8192];
  __shared__ u16 xc[8192];
  enc_body(lw, xc, blockIdx.x, threadIdx.x, x, enc_b, encF, h0F, Nn);
}

// ---------------- kB: hist<1> (short, FIRST) + enc (long) — both ready after reduce0 ----------------
__global__ void __launch_bounds__(256, 2)
kB_kernel(const int* __restrict__ ei, const float* __restrict__ dv, float* __restrict__ partial,
          int E, int Nn, int NB, int chunk, int nbHist,
          const float* __restrict__ x, const float* __restrict__ enc_b,
          const u16* __restrict__ encF, u32* __restrict__ h0F)
{
  __shared__ __align__(16) char smem[65536];
  const int b = blockIdx.x, tid = threadIdx.x;
  if(b < nbHist){
    hist_body<1>((float*)smem, b, tid, ei + E, ei, dv, partial, E, Nn, NB, chunk);
  } else {
    enc_body((u16*)smem, (u16*)(smem + 16384), b - nbHist, tid, x, enc_b, encF, h0F, Nn);
  }
}

// ---------------- lay: R19-verified + inline coef (R22-verified) ----------------
template<bool INLC>
__global__ void __launch_bounds__(256, 2)
lay_kernel(const float* __restrict__ W_b, const float* __restrict__ ext_w,
           const float* __restrict__ beta, const float* __restrict__ dec_b,
           const float* __restrict__ coef, const float* __restrict__ dv,
           const float* __restrict__ partial, int NB,
           const u32* __restrict__ h0F,
           const u16* __restrict__ weffF, const u16* __restrict__ decB,
           float* __restrict__ out, int Nn)
{
  __shared__ u16 lw[16384];        // 32 KB layer weights
  __shared__ u32 hns[16][256];     // 16 KB: pass-0 h carry (thread-private slots)

  const int tid  = threadIdx.x;
  const int lane = tid & 63;
  const int wv   = tid >> 6;
  const int hi   = lane >> 5;
  const int ln   = lane & 31;
  const int nib  = wv * 32 + ln;
  const int node = blockIdx.x * 128 + nib;
  const int nd   = node < Nn ? node : (Nn - 1);

  float cf;
  if(INLC){
    const size_t NnPad = (size_t)NB << 14;
    float s = 0.f;
    #pragma unroll 4
    for(int sl = 0; sl < NSL; sl++) s += partial[(size_t)sl * NnPad + nd];
    cf = dv[nd] * s;
  } else {
    cf = coef[nd];
  }

  u32 hp[32];
  const u32* srcH = h0F + (size_t)blockIdx.x * 8192;
  #pragma unroll
  for(int m = 0; m < 32; m++)
    hp[m] = srcH[m * 256 + tid];

  for(int l = 0; l < NL; l++){
    __syncthreads();
    stage32k_async(lw, weffF + l * 16384, wv, lane);
    __syncthreads();

    const float bet = beta[l];

    #pragma unroll
    for(int P = 0; P < 2; P++){
      f32x16 a0, a1;
      #pragma unroll
      for(int i = 0; i < 16; i++){ a0[i] = 0.f; a1[i] = 0.f; }

      #pragma unroll
      for(int ks = 0; ks < 8; ks++){
        const int wbase = (ks >> 1) * 8 + 4 * (ks & 1);
        bf16x8 B = buildBp(hp[wbase+0], hp[wbase+1], hp[wbase+2], hp[wbase+3], hi);
        const bf16x8 A0 = *(const bf16x8*)(lw + (((((2*P+0) * 8 + ks) * 2 + hi) * 32 + ln) * 8));
        const bf16x8 A1 = *(const bf16x8*)(lw + (((((2*P+1) * 8 + ks) * 2 + hi) * 32 + ln) * 8));
        a0 = __builtin_amdgcn_mfma_f32_32x32x16_bf16(A0, B, a0, 0, 0, 0);
        a1 = __builtin_amdgcn_mfma_f32_32x32x16_bf16(A1, B, a1, 0, 0, 0);
      }

      #pragma unroll
      for(int t = 0; t < 2; t++){
        const int nt = 2*P + t;
        f32x16& a = t ? a1 : a0;
        #pragma unroll
        for(int q = 0; q < 4; q++){
          const int fb = nt * 32 + 8 * q + 4 * hi;
          float4 wb = *(const float4*)(W_b   + l * HDIM + fb);
          float4 ew = *(const float4*)(ext_w + l * HDIM + fb);
          #pragma unroll
          for(int r2 = 0; r2 < 4; r2++){
            const int r = 4 * q + r2;
            float wbv = (r2==0)?wb.x:(r2==1)?wb.y:(r2==2)?wb.z:wb.w;
            float ewv = (r2==0)?ew.x:(r2==1)?ew.y:(r2==2)?ew.z:ew.w;
            u32 w0 = srcH[(nt * 8 + (r >> 1)) * 256 + tid];   // L2-resident h0 re-read
            u32 wc = hp[nt * 8 + (r >> 1)];
            float h0v = ubf((r & 1) ? (w0 >> 16) : (w0 & 0xffffu));
            float hv  = ubf((r & 1) ? (wc >> 16) : (wc & 0xffffu));
            float o = cf * (a[r] + wbv) - hv * ewv - bet * h0v;
            a[r] = hv + 0.1f * fmaxf(o, 0.f);
          }
        }
        #pragma unroll
        for(int m = 0; m < 8; m++){
          u32 w = pk(a[2*m], a[2*m+1]);
          if(P == 0) hns[nt * 8 + m][tid] = w;   // carry in LDS (thread-private)
          else       hp[nt * 8 + m] = w;
        }
      }
    }
    #pragma unroll
    for(int m = 0; m < 16; m++) hp[m] = hns[m][tid];
  }

  // ---- decoder: direct from L2 (verified path) ----
  f32x16 d0, d1;
  #pragma unroll
  for(int i = 0; i < 16; i++){ d0[i] = 0.f; d1[i] = 0.f; }

  #pragma unroll
  for(int ks = 0; ks < 8; ks++){
    const int wbase = (ks >> 1) * 8 + 4 * (ks & 1);
    bf16x8 B = buildBp(hp[wbase+0], hp[wbase+1], hp[wbase+2], hp[wbase+3], hi);
    const bf16x8 A0 = *(const bf16x8*)(decB + (0 * 32 + ln) * HDIM + ks * 16 + hi * 8);
    const bf16x8 A1 = *(const bf16x8*)(decB + (1 * 32 + ln) * HDIM + ks * 16 + hi * 8);
    d0 = __builtin_amdgcn_mfma_f32_32x32x16_bf16(A0, B, d0, 0, 0, 0);
    d1 = __builtin_amdgcn_mfma_f32_32x32x16_bf16(A1, B, d1, 0, 0, 0);
  }

  if(node < Nn){
    #pragma unroll
    for(int nt = 0; nt < 2; nt++){
      const f32x16& d = nt ? d1 : d0;
      #pragma unroll
      for(int q = 0; q < 4; q++){
        if(nt == 0 || q == 0){
          const int c0 = nt * 32 + 8 * q + 4 * hi;
          float4 db = *(const float4*)(dec_b + c0);
          float4 v;
          v.x = d[4*q+0] + db.x;
          v.y = d[4*q+1] + db.y;
          v.z = d[4*q+2] + db.z;
          v.w = d[4*q+3] + db.w;
          *(float4*)(out + (size_t)node * NCLS + c0) = v;
        }
      }
    }
  }
}

extern "C" void kernel_launch(void* const* d_in, const int* in_sizes, int n_in,
                              void* d_out, int out_size, void* d_ws, size_t ws_size,
                              hipStream_t stream){
  (void)n_in; (void)out_size;
  const float* x     = (const float*)d_in[0];
  const int*   ei    = (const int*)  d_in[1];
  const float* encW  = (const float*)d_in[2];
  const float* enc_b = (const float*)d_in[3];
  const float* Wraw  = (const float*)d_in[4];
  const float* W_b   = (const float*)d_in[5];
  const float* ext_w = (const float*)d_in[6];
  const float* beta  = (const float*)d_in[7];
  const float* decW  = (const float*)d_in[8];
  const float* dec_b = (const float*)d_in[9];
  float* out = (float*)d_out;
  const int Nn = in_sizes[0] / FIN;
  const int E  = in_sizes[1] / 2;
  const int nBlk = (Nn + 127) / 128;
  const int NB   = (Nn + BN - 1) / BN;
  const int chunk = (((E + NSL - 1) / NSL) + 3) & ~3;
  const int nbHist = NB * NSL;

  char* ws = (char*)d_ws;
  size_t szN = ((size_t)Nn * 4 + 511) & ~(size_t)511;
  float* coef = (float*)(ws);
  float* dv   = (float*)(ws + szN);               // fast: dinv; fallback: raw deg
  u16* encF   = (u16*)(ws + 2 * szN);
  u16* weffF  = (u16*)(ws + 2 * szN + 65536);
  u16* decB   = (u16*)(ws + 2 * szN + 65536 + 131072);
  u32* h0F    = (u32*)(ws + 2 * szN + 65536 + 131072 + 16384);
  float* partial = (float*)(ws + 2 * szN + 65536 + 131072 + 16384 + (size_t)nBlk * 32768);
  const size_t partialBytes = (size_t)NSL * ((size_t)NB << 14) * 4;
  const size_t need = 2 * szN + 65536 + 131072 + 16384 + (size_t)nBlk * 32768 + partialBytes;
  const bool fast = ws_size >= need;

  const int ngrid = (Nn + 255) / 256;
  if(fast){
    // chain: [hist0 || prep] -> reduce0(dv) -> [hist1 || enc] -> lay (coef inlined)
    kP_kernel<<<nbHist + 288, 256, 0, stream>>>(encW, Wraw, decW, encF, weffF, decB,
                                                ei, partial, E, Nn, NB, chunk, nbHist);
    reduce_kernel<0><<<ngrid, 256, 0, stream>>>(partial, dv, dv, Nn, NB, NSL);
    kB_kernel<<<nbHist + nBlk, 256, 0, stream>>>(ei, dv, partial, E, Nn, NB, chunk, nbHist,
                                                 x, enc_b, encF, h0F);
    lay_kernel<true><<<nBlk, 256, 0, stream>>>(W_b, ext_w, beta, dec_b, coef, dv, partial, NB,
                                               h0F, weffF, decB, out, Nn);
  } else {
    const int egrid = (int)((E / 8 + 255) / 256) + 1;
    hipMemsetAsync(ws, 0, 2 * szN, stream);
    prep_kernel<<<1152, 64, 0, stream>>>(encW, Wraw, decW, encF, weffF, decB);
    deg_kernel <<<egrid, 256, 0, stream>>>(ei, dv, E);
    coef_kernel<<<egrid, 256, 0, stream>>>(ei, dv, coef, E);
    enc_kernel <<<nBlk, 256, 0, stream>>>(x, enc_b, encF, h0F, Nn);
    lay_kernel<false><<<nBlk, 256, 0, stream>>>(W_b, ext_w, beta, dec_b, coef, dv, partial, NB,
                                                h0F, weffF, decB, out, Nn);
  }
}